// Round 1
// baseline (1482.314 us; speedup 1.0000x reference)
//
#include <hip/hip_runtime.h>
#include <hip/hip_bf16.h>
#include <math.h>

// Problem constants (from setup_inputs):
//   B=4, Lq=4096, C=768, NH=12, d=64, NP=4, nl=1, H=W=64, Lin=4096, hid=192
#define B_    4
#define LQ    4096
#define CC    768
#define NH_   12
#define DH    64
#define NP_   4
#define HH    64
#define WW    64
#define HID   192
#define ROWS  (B_ * LQ)          // 16384
#define EPS_  1e-5f

// ---------------------------------------------------------------------------
// LayerNorm: one block (256 thr) per row of C=768
// ---------------------------------------------------------------------------
__inline__ __device__ float wave_sum64(float v) {
    #pragma unroll
    for (int o = 32; o > 0; o >>= 1) v += __shfl_down(v, o, 64);
    return v;
}

__global__ void ln_kernel(const float* __restrict__ x, const float* __restrict__ g,
                          const float* __restrict__ b, float* __restrict__ y, int C) {
    int row = blockIdx.x;
    const float* xr = x + (size_t)row * C;
    float* yr = y + (size_t)row * C;
    float s = 0.f, s2 = 0.f;
    for (int i = threadIdx.x; i < C; i += blockDim.x) {
        float v = xr[i];
        s += v; s2 += v * v;
    }
    __shared__ float red[8];
    float ws = wave_sum64(s), ws2 = wave_sum64(s2);
    int w = threadIdx.x >> 6;
    if ((threadIdx.x & 63) == 0) { red[w] = ws; red[4 + w] = ws2; }
    __syncthreads();
    float S  = red[0] + red[1] + red[2] + red[3];
    float S2 = red[4] + red[5] + red[6] + red[7];
    float mean = S / C;
    float var  = S2 / C - mean * mean;
    float inv  = rsqrtf(var + EPS_);
    for (int i = threadIdx.x; i < C; i += blockDim.x) {
        yr[i] = (xr[i] - mean) * inv * g[i] + b[i];
    }
}

// ---------------------------------------------------------------------------
// GEMM: out[m, coff+n] = act( A[m,:] @ W[:,n] + bias[n] ) + res[m, coff+n]
// A: [M,K] row-major, W: [K,N] row-major. 64x64 tile, 256 threads, 4x4/thread.
// ---------------------------------------------------------------------------
#define BM 64
#define BN 64
#define BK 16

__global__ __launch_bounds__(256)
void gemm_kernel(const float* __restrict__ A, const float* __restrict__ W,
                 const float* __restrict__ bias, const float* __restrict__ res,
                 float* __restrict__ out, int M, int K, int N, int ldc,
                 int coff, int act_gelu) {
    __shared__ float As[BK][BM + 1];
    __shared__ float Bs[BK][BN + 1];
    int bm = blockIdx.y * BM, bn = blockIdx.x * BN;
    int t  = threadIdx.x;
    int tx = t & 15, ty = t >> 4;
    float acc[4][4] = {};

    for (int k0 = 0; k0 < K; k0 += BK) {
        // Stage A tile (64 rows x 16 k), store transposed As[k][m]
        {
            int kk = t & 15, rr = t >> 4;
            #pragma unroll
            for (int p = 0; p < 4; ++p) {
                int m = bm + rr + p * 16;   // M is always a multiple of 64
                As[kk][rr + p * 16] = A[(size_t)m * K + k0 + kk];
            }
        }
        // Stage W tile (16 k x 64 n)
        {
            int nn = t & 63, kk = t >> 6;
            #pragma unroll
            for (int p = 0; p < 4; ++p) {
                int n = bn + nn;
                float v = 0.f;
                if (n < N) v = W[(size_t)(k0 + kk + p * 4) * N + n];
                Bs[kk + p * 4][nn] = v;
            }
        }
        __syncthreads();
        #pragma unroll
        for (int kk = 0; kk < BK; ++kk) {
            float a[4], bv[4];
            #pragma unroll
            for (int i = 0; i < 4; ++i) a[i]  = As[kk][ty + 16 * i];
            #pragma unroll
            for (int j = 0; j < 4; ++j) bv[j] = Bs[kk][tx + 16 * j];
            #pragma unroll
            for (int i = 0; i < 4; ++i)
                #pragma unroll
                for (int j = 0; j < 4; ++j)
                    acc[i][j] += a[i] * bv[j];
        }
        __syncthreads();
    }

    #pragma unroll
    for (int i = 0; i < 4; ++i) {
        int m = bm + ty + 16 * i;
        #pragma unroll
        for (int j = 0; j < 4; ++j) {
            int n = bn + tx + 16 * j;
            if (n < N) {
                float v = acc[i][j];
                if (bias) v += bias[n];
                if (act_gelu) v = 0.5f * v * (1.f + erff(v * 0.70710678118f));
                size_t oi = (size_t)m * ldc + coff + n;
                if (res) v += res[oi];
                out[oi] = v;
            }
        }
    }
}

// ---------------------------------------------------------------------------
// Deformable sampling: one wave per (b, q, h); lane = channel dd (0..63).
// value:  [B, Lin, NH*DH]   offatt: [B*Lq, 144] (96 offsets + 48 att logits)
// refp:   [B, Lq, 1, 2]     out:    [B, Lq, C]  (C index = h*64 + dd)
// ---------------------------------------------------------------------------
__global__ __launch_bounds__(256)
void sample_kernel(const float* __restrict__ value, const float* __restrict__ offatt,
                   const float* __restrict__ refp, float* __restrict__ out) {
    int wid  = blockIdx.x * (blockDim.x >> 6) + (threadIdx.x >> 6);
    int lane = threadIdx.x & 63;
    // wid = (b*Lq + q)*NH + h
    int h  = wid % NH_;
    int bq = wid / NH_;

    const float* oa = offatt + (size_t)bq * 144;
    float rx = refp[(size_t)bq * 2 + 0];
    float ry = refp[(size_t)bq * 2 + 1];

    // softmax over the 4 attention logits of this head
    float l0 = oa[96 + h * 4 + 0], l1 = oa[96 + h * 4 + 1];
    float l2 = oa[96 + h * 4 + 2], l3 = oa[96 + h * 4 + 3];
    float mx = fmaxf(fmaxf(l0, l1), fmaxf(l2, l3));
    float e0 = __expf(l0 - mx), e1 = __expf(l1 - mx);
    float e2 = __expf(l2 - mx), e3 = __expf(l3 - mx);
    float rs = 1.f / (e0 + e1 + e2 + e3);
    float wp[4] = {e0 * rs, e1 * rs, e2 * rs, e3 * rs};

    int b = bq / LQ;
    const float* vbase = value + (size_t)b * (LQ * CC) + h * DH + lane;

    float acc = 0.f;
    #pragma unroll
    for (int p = 0; p < NP_; ++p) {
        float ox = oa[h * 8 + p * 2 + 0];
        float oy = oa[h * 8 + p * 2 + 1];
        // pixel coords: (ref + off/W)*W - 0.5  ==  ref*W + off - 0.5
        float x = rx * (float)WW + ox - 0.5f;
        float y = ry * (float)HH + oy - 0.5f;
        float x0f = floorf(x), y0f = floorf(y);
        float wx1 = x - x0f, wy1 = y - y0f;
        float wx0 = 1.f - wx1, wy0 = 1.f - wy1;
        int x0 = (int)x0f, y0 = (int)y0f;
        float sv = 0.f;
        {
            int xi = x0, yi = y0; float wt = wx0 * wy0;
            if (xi >= 0 && xi < WW && yi >= 0 && yi < HH)
                sv += wt * vbase[(size_t)(yi * WW + xi) * CC];
        }
        {
            int xi = x0 + 1, yi = y0; float wt = wx1 * wy0;
            if (xi >= 0 && xi < WW && yi >= 0 && yi < HH)
                sv += wt * vbase[(size_t)(yi * WW + xi) * CC];
        }
        {
            int xi = x0, yi = y0 + 1; float wt = wx0 * wy1;
            if (xi >= 0 && xi < WW && yi >= 0 && yi < HH)
                sv += wt * vbase[(size_t)(yi * WW + xi) * CC];
        }
        {
            int xi = x0 + 1, yi = y0 + 1; float wt = wx1 * wy1;
            if (xi >= 0 && xi < WW && yi >= 0 && yi < HH)
                sv += wt * vbase[(size_t)(yi * WW + xi) * CC];
        }
        acc += wp[p] * sv;
    }
    out[(size_t)bq * CC + h * DH + lane] = acc;
}

// ---------------------------------------------------------------------------
// Launch
// ---------------------------------------------------------------------------
extern "C" void kernel_launch(void* const* d_in, const int* in_sizes, int n_in,
                              void* d_out, int out_size, void* d_ws, size_t ws_size,
                              hipStream_t stream) {
    const float* query = (const float*)d_in[0];
    const float* refp  = (const float*)d_in[1];
    const float* feat  = (const float*)d_in[2];
    // d_in[3] spatial_shapes, d_in[4] level_start_index, d_in[5] H, d_in[6] W (hardcoded)
    const float* qn_g  = (const float*)d_in[7];
    const float* qn_b  = (const float*)d_in[8];
    const float* fn_g  = (const float*)d_in[9];
    const float* fn_b  = (const float*)d_in[10];
    const float* Wv    = (const float*)d_in[11];
    const float* bv    = (const float*)d_in[12];
    const float* Woff  = (const float*)d_in[13];
    const float* boff  = (const float*)d_in[14];
    const float* Watt  = (const float*)d_in[15];
    const float* batt  = (const float*)d_in[16];
    const float* Wout  = (const float*)d_in[17];
    const float* bout  = (const float*)d_in[18];
    const float* ffn_g = (const float*)d_in[19];
    const float* ffn_b = (const float*)d_in[20];
    const float* W1    = (const float*)d_in[21];
    const float* b1    = (const float*)d_in[22];
    const float* W2    = (const float*)d_in[23];
    const float* b2    = (const float*)d_in[24];
    float* out = (float*)d_out;

    // workspace: ws0, ws1: ROWS*C floats each; ws2: ROWS*192 floats
    float* ws0 = (float*)d_ws;                       // 16384*768
    float* ws1 = ws0 + (size_t)ROWS * CC;            // 16384*768
    float* ws2 = ws1 + (size_t)ROWS * CC;            // 16384*192 (>=144)

    dim3 blk(256);

    // 1. qn = LN(query) -> ws0 ; 2. fn = LN(feat) -> ws1
    ln_kernel<<<ROWS, blk, 0, stream>>>(query, qn_g, qn_b, ws0, CC);
    ln_kernel<<<ROWS, blk, 0, stream>>>(feat,  fn_g, fn_b, ws1, CC);

    // 3. offatt[:, 0:96]  = qn @ Woff + boff
    {
        dim3 grid((96 + BN - 1) / BN, ROWS / BM);
        gemm_kernel<<<grid, blk, 0, stream>>>(ws0, Woff, boff, nullptr, ws2,
                                              ROWS, CC, 96, 144, 0, 0);
    }
    // 4. offatt[:, 96:144] = qn @ Watt + batt
    {
        dim3 grid((48 + BN - 1) / BN, ROWS / BM);
        gemm_kernel<<<grid, blk, 0, stream>>>(ws0, Watt, batt, nullptr, ws2,
                                              ROWS, CC, 48, 144, 96, 0);
    }
    // 5. value = fn @ Wv + bv -> ws0 (qn dead)
    {
        dim3 grid(CC / BN, ROWS / BM);
        gemm_kernel<<<grid, blk, 0, stream>>>(ws1, Wv, bv, nullptr, ws0,
                                              ROWS, CC, CC, CC, 0, 0);
    }
    // 6. sampled attention -> ws1 (fn dead)
    {
        int waves = ROWS * NH_;             // 196608
        sample_kernel<<<waves / 4, blk, 0, stream>>>(ws0, ws2, refp, ws1);
    }
    // 7. attnres = query + sampout @ Wout + bout -> ws0 (value dead)
    {
        dim3 grid(CC / BN, ROWS / BM);
        gemm_kernel<<<grid, blk, 0, stream>>>(ws1, Wout, bout, query, ws0,
                                              ROWS, CC, CC, CC, 0, 0);
    }
    // 8. h = LN(attnres) -> ws1
    ln_kernel<<<ROWS, blk, 0, stream>>>(ws0, ffn_g, ffn_b, ws1, CC);
    // 9. h1 = gelu(h @ W1 + b1) -> ws2
    {
        dim3 grid(HID / BN, ROWS / BM);
        gemm_kernel<<<grid, blk, 0, stream>>>(ws1, W1, b1, nullptr, ws2,
                                              ROWS, CC, HID, HID, 0, 1);
    }
    // 10. out = attnres + h1 @ W2 + b2
    {
        dim3 grid(CC / BN, ROWS / BM);
        gemm_kernel<<<grid, blk, 0, stream>>>(ws2, W2, b2, ws0, out,
                                              ROWS, HID, CC, CC, 0, 0);
    }
}

// Round 2
// 1213.103 us; speedup vs baseline: 1.2219x; 1.2219x over previous
//
#include <hip/hip_runtime.h>
#include <hip/hip_bf16.h>
#include <math.h>

// Problem constants:
//   B=4, Lq=4096, C=768, NH=12, d=64, NP=4, nl=1, H=W=64, Lin=4096, hid=192
#define B_    4
#define LQ    4096
#define CC    768
#define NH_   12
#define DH    64
#define NP_   4
#define HH    64
#define WW    64
#define HID   192
#define ROWS  (B_ * LQ)          // 16384
#define EPS_  1e-5f

typedef __bf16 bf16x8 __attribute__((ext_vector_type(8)));
typedef float  f32x4  __attribute__((ext_vector_type(4)));

// ---------------------------------------------------------------------------
// LayerNorm: one block (256 thr) per row of C=768 -> bf16 output
// ---------------------------------------------------------------------------
__inline__ __device__ float wave_sum64(float v) {
    #pragma unroll
    for (int o = 32; o > 0; o >>= 1) v += __shfl_down(v, o, 64);
    return v;
}

__global__ void ln_kernel_bf(const float* __restrict__ x, const float* __restrict__ g,
                             const float* __restrict__ b, __bf16* __restrict__ y, int C) {
    int row = blockIdx.x;
    const float* xr = x + (size_t)row * C;
    __bf16* yr = y + (size_t)row * C;
    float s = 0.f, s2 = 0.f;
    for (int i = threadIdx.x; i < C; i += blockDim.x) {
        float v = xr[i];
        s += v; s2 += v * v;
    }
    __shared__ float red[8];
    float ws = wave_sum64(s), ws2 = wave_sum64(s2);
    int w = threadIdx.x >> 6;
    if ((threadIdx.x & 63) == 0) { red[w] = ws; red[4 + w] = ws2; }
    __syncthreads();
    float S  = red[0] + red[1] + red[2] + red[3];
    float S2 = red[4] + red[5] + red[6] + red[7];
    float mean = S / C;
    float var  = S2 / C - mean * mean;
    float inv  = rsqrtf(var + EPS_);
    for (int i = threadIdx.x; i < C; i += blockDim.x) {
        yr[i] = (__bf16)((xr[i] - mean) * inv * g[i] + b[i]);
    }
}

// ---------------------------------------------------------------------------
// bf16 MFMA GEMM: out[m,n] = act( A[m,:] @ W[:,n] + bias[n] ) + res[m,n]
//   A:   bf16 [M,K] row-major (K multiple of 32)
//   W:   f32, fused pair: n < Nsplit -> Wa[k*Nsplit+n], else Wb[k*(N-Nsplit)+(n-Nsplit)]
//        (converted to bf16 during LDS staging)
//   out: f32 or bf16 (flag), ld = N
// Tile: 128x128, BK=32, 256 threads = 4 waves (2x2), 4x4 16x16x32 MFMA per wave
// ---------------------------------------------------------------------------
#define LDS_STRIDE 40   // bf16 elems per row (32 + 8 pad); 80 B, 16B-aligned

__global__ __launch_bounds__(256)
void mfma_gemm(const __bf16* __restrict__ A,
               const float* __restrict__ Wa, const float* __restrict__ ba, int Nsplit,
               const float* __restrict__ Wb, const float* __restrict__ bb,
               const float* __restrict__ res, void* __restrict__ out,
               int M, int K, int N, int do_gelu, int out_bf16) {
    __shared__ __bf16 As[128 * LDS_STRIDE];
    __shared__ __bf16 Bs[128 * LDS_STRIDE];

    int bm = blockIdx.y * 128, bn = blockIdx.x * 128;
    int t = threadIdx.x;
    int lane = t & 63, wave = t >> 6;
    int wm = wave & 1, wn = wave >> 1;

    f32x4 acc[4][4] = {};

    // A staging indices: thread t stages rows rrA and rrA+64, k-chunk kcA (8 bf16)
    int rrA = t >> 2, kcA = t & 3;
    // B staging indices: thread t stages column nlB, k-half khB (16 values)
    int nlB = t & 127, khB = t >> 7;
    int nglob = bn + nlB;
    bool bvalid = nglob < N;
    bool whichA = nglob < Nsplit;
    const float* colbase = whichA ? (Wa + nglob) : (Wb + (nglob - Nsplit));
    int cstride = whichA ? Nsplit : (N - Nsplit);

    // fragment read indices
    int kq = lane >> 4;            // 0..3
    int rfrag = wm * 64 + (lane & 15);
    int nfrag = wn * 64 + (lane & 15);

    for (int k0 = 0; k0 < K; k0 += 32) {
        // --- load globals into registers ---
        bf16x8 a0 = *(const bf16x8*)(A + (size_t)(bm + rrA) * K + k0 + kcA * 8);
        bf16x8 a1 = *(const bf16x8*)(A + (size_t)(bm + rrA + 64) * K + k0 + kcA * 8);
        __bf16 tmp[16];
        #pragma unroll
        for (int j = 0; j < 16; ++j) {
            int k = k0 + khB * 16 + j;
            float v = bvalid ? colbase[(size_t)k * cstride] : 0.f;
            tmp[j] = (__bf16)v;
        }
        __syncthreads();           // prior iteration's LDS reads done
        // --- store to LDS ---
        *(bf16x8*)&As[rrA * LDS_STRIDE + kcA * 8] = a0;
        *(bf16x8*)&As[(rrA + 64) * LDS_STRIDE + kcA * 8] = a1;
        int boff = nlB * LDS_STRIDE + ((khB ^ (nlB & 1)) * 16);
        *(bf16x8*)&Bs[boff]     = *(bf16x8*)&tmp[0];
        *(bf16x8*)&Bs[boff + 8] = *(bf16x8*)&tmp[8];
        __syncthreads();
        // --- fragments + MFMA ---
        bf16x8 afr[4], bfr[4];
        #pragma unroll
        for (int i = 0; i < 4; ++i)
            afr[i] = *(const bf16x8*)&As[(rfrag + i * 16) * LDS_STRIDE + kq * 8];
        #pragma unroll
        for (int j = 0; j < 4; ++j) {
            int ne = nfrag + j * 16;
            bfr[j] = *(const bf16x8*)&Bs[ne * LDS_STRIDE + (((kq >> 1) ^ (ne & 1)) * 16) + (kq & 1) * 8];
        }
        #pragma unroll
        for (int i = 0; i < 4; ++i)
            #pragma unroll
            for (int j = 0; j < 4; ++j)
                acc[i][j] = __builtin_amdgcn_mfma_f32_16x16x32_bf16(afr[i], bfr[j], acc[i][j], 0, 0, 0);
    }

    // --- epilogue ---
    int rowq = lane >> 4;
    int colj[4]; float biasj[4];
    #pragma unroll
    for (int j = 0; j < 4; ++j) {
        int c = bn + wn * 64 + j * 16 + (lane & 15);
        colj[j] = c;
        biasj[j] = (c < N) ? ((c < Nsplit) ? ba[c] : bb[c - Nsplit]) : 0.f;
    }
    #pragma unroll
    for (int i = 0; i < 4; ++i) {
        #pragma unroll
        for (int r = 0; r < 4; ++r) {
            int m = bm + wm * 64 + i * 16 + rowq * 4 + r;
            #pragma unroll
            for (int j = 0; j < 4; ++j) {
                if (colj[j] < N) {
                    float v = acc[i][j][r] + biasj[j];
                    if (do_gelu) v = 0.5f * v * (1.f + erff(v * 0.70710678118f));
                    size_t oi = (size_t)m * N + colj[j];
                    if (res) v += res[oi];
                    if (out_bf16) ((__bf16*)out)[oi] = (__bf16)v;
                    else          ((float*)out)[oi]  = v;
                }
            }
        }
    }
}

// ---------------------------------------------------------------------------
// Deformable sampling: one wave per (b, q, h); lane = channel dd (0..63).
// value: f32 [B, Lin, NH*DH]; offatt: f32 [B*Lq, 144]; out: bf16 [B*Lq, C]
// ---------------------------------------------------------------------------
__global__ __launch_bounds__(256)
void sample_kernel(const float* __restrict__ value, const float* __restrict__ offatt,
                   const float* __restrict__ refp, __bf16* __restrict__ out) {
    int wid  = blockIdx.x * (blockDim.x >> 6) + (threadIdx.x >> 6);
    int lane = threadIdx.x & 63;
    int h  = wid % NH_;
    int bq = wid / NH_;

    const float* oa = offatt + (size_t)bq * 144;
    float rx = refp[(size_t)bq * 2 + 0];
    float ry = refp[(size_t)bq * 2 + 1];

    float l0 = oa[96 + h * 4 + 0], l1 = oa[96 + h * 4 + 1];
    float l2 = oa[96 + h * 4 + 2], l3 = oa[96 + h * 4 + 3];
    float mx = fmaxf(fmaxf(l0, l1), fmaxf(l2, l3));
    float e0 = __expf(l0 - mx), e1 = __expf(l1 - mx);
    float e2 = __expf(l2 - mx), e3 = __expf(l3 - mx);
    float rs = 1.f / (e0 + e1 + e2 + e3);
    float wp[4] = {e0 * rs, e1 * rs, e2 * rs, e3 * rs};

    int b = bq / LQ;
    const float* vbase = value + (size_t)b * (LQ * CC) + h * DH + lane;

    float acc = 0.f;
    #pragma unroll
    for (int p = 0; p < NP_; ++p) {
        float ox = oa[h * 8 + p * 2 + 0];
        float oy = oa[h * 8 + p * 2 + 1];
        float x = rx * (float)WW + ox - 0.5f;
        float y = ry * (float)HH + oy - 0.5f;
        float x0f = floorf(x), y0f = floorf(y);
        float wx1 = x - x0f, wy1 = y - y0f;
        float wx0 = 1.f - wx1, wy0 = 1.f - wy1;
        int x0 = (int)x0f, y0 = (int)y0f;
        float sv = 0.f;
        if (x0 >= 0 && x0 < WW && y0 >= 0 && y0 < HH)
            sv += wx0 * wy0 * vbase[(size_t)(y0 * WW + x0) * CC];
        if (x0 + 1 >= 0 && x0 + 1 < WW && y0 >= 0 && y0 < HH)
            sv += wx1 * wy0 * vbase[(size_t)(y0 * WW + x0 + 1) * CC];
        if (x0 >= 0 && x0 < WW && y0 + 1 >= 0 && y0 + 1 < HH)
            sv += wx0 * wy1 * vbase[(size_t)((y0 + 1) * WW + x0) * CC];
        if (x0 + 1 >= 0 && x0 + 1 < WW && y0 + 1 >= 0 && y0 + 1 < HH)
            sv += wx1 * wy1 * vbase[(size_t)((y0 + 1) * WW + x0 + 1) * CC];
        acc += wp[p] * sv;
    }
    out[(size_t)bq * CC + h * DH + lane] = (__bf16)acc;
}

// ---------------------------------------------------------------------------
// Launch
// ---------------------------------------------------------------------------
extern "C" void kernel_launch(void* const* d_in, const int* in_sizes, int n_in,
                              void* d_out, int out_size, void* d_ws, size_t ws_size,
                              hipStream_t stream) {
    const float* query = (const float*)d_in[0];
    const float* refp  = (const float*)d_in[1];
    const float* feat  = (const float*)d_in[2];
    const float* qn_g  = (const float*)d_in[7];
    const float* qn_b  = (const float*)d_in[8];
    const float* fn_g  = (const float*)d_in[9];
    const float* fn_b  = (const float*)d_in[10];
    const float* Wv    = (const float*)d_in[11];
    const float* bv    = (const float*)d_in[12];
    const float* Woff  = (const float*)d_in[13];
    const float* boff  = (const float*)d_in[14];
    const float* Watt  = (const float*)d_in[15];
    const float* batt  = (const float*)d_in[16];
    const float* Wout  = (const float*)d_in[17];
    const float* bout  = (const float*)d_in[18];
    const float* ffn_g = (const float*)d_in[19];
    const float* ffn_b = (const float*)d_in[20];
    const float* W1    = (const float*)d_in[21];
    const float* b1    = (const float*)d_in[22];
    const float* W2    = (const float*)d_in[23];
    const float* b2    = (const float*)d_in[24];
    float* out = (float*)d_out;

    // workspace layout (bytes):
    char* ws = (char*)d_ws;
    float*  value_f  = (float*)ws;                               // 16384*768*4 = 50.33 MB (also attnres)
    float*  attnres  = value_f;                                  // reuse (value dead after sampler)
    float*  offatt_f = (float*)(ws + (size_t)50331648);          // 16384*144*4 = 9.44 MB
    __bf16* h1_bf    = (__bf16*)offatt_f;                        // reuse (offatt dead after sampler)
    __bf16* qn_bf    = (__bf16*)(ws + (size_t)50331648 + 9437184);        // 25.17 MB
    __bf16* h_bf     = qn_bf;                                    // reuse
    __bf16* fn_bf    = (__bf16*)(ws + (size_t)50331648 + 9437184 + 25165824); // 25.17 MB
    __bf16* samp_bf  = fn_bf;                                    // reuse

    dim3 blk(256);

    // 1-2. LayerNorms -> bf16
    ln_kernel_bf<<<ROWS, blk, 0, stream>>>(query, qn_g, qn_b, qn_bf, CC);
    ln_kernel_bf<<<ROWS, blk, 0, stream>>>(feat,  fn_g, fn_b, fn_bf, CC);

    // 3. offatt = qn @ [Woff | Watt] + [boff | batt]  (N=144, f32 out)
    {
        dim3 grid(2, ROWS / 128);
        mfma_gemm<<<grid, blk, 0, stream>>>(qn_bf, Woff, boff, 96, Watt, batt,
                                            nullptr, offatt_f, ROWS, CC, 144, 0, 0);
    }
    // 4. value = fn @ Wv + bv (f32 out)
    {
        dim3 grid(6, ROWS / 128);
        mfma_gemm<<<grid, blk, 0, stream>>>(fn_bf, Wv, bv, CC, nullptr, nullptr,
                                            nullptr, value_f, ROWS, CC, CC, 0, 0);
    }
    // 5. deformable sampling -> bf16
    {
        int waves = ROWS * NH_;
        sample_kernel<<<waves / 4, blk, 0, stream>>>(value_f, offatt_f, refp, samp_bf);
    }
    // 6. attnres = query + samp @ Wout + bout (f32 out)
    {
        dim3 grid(6, ROWS / 128);
        mfma_gemm<<<grid, blk, 0, stream>>>(samp_bf, Wout, bout, CC, nullptr, nullptr,
                                            query, attnres, ROWS, CC, CC, 0, 0);
    }
    // 7. h = LN(attnres) -> bf16
    ln_kernel_bf<<<ROWS, blk, 0, stream>>>(attnres, ffn_g, ffn_b, h_bf, CC);
    // 8. h1 = gelu(h @ W1 + b1) -> bf16 (N=192)
    {
        dim3 grid(2, ROWS / 128);
        mfma_gemm<<<grid, blk, 0, stream>>>(h_bf, W1, b1, HID, nullptr, nullptr,
                                            nullptr, h1_bf, ROWS, CC, HID, 1, 1);
    }
    // 9. out = attnres + h1 @ W2 + b2 (K=192, f32 out)
    {
        dim3 grid(6, ROWS / 128);
        mfma_gemm<<<grid, blk, 0, stream>>>(h1_bf, W2, b2, CC, nullptr, nullptr,
                                            attnres, out, ROWS, HID, CC, 0, 0);
    }
}

// Round 3
// 682.295 us; speedup vs baseline: 2.1725x; 1.7780x over previous
//
#include <hip/hip_runtime.h>
#include <hip/hip_bf16.h>
#include <math.h>

// Problem constants:
//   B=4, Lq=4096, C=768, NH=12, d=64, NP=4, nl=1, H=W=64, Lin=4096, hid=192
#define B_    4
#define LQ    4096
#define CC    768
#define NH_   12
#define DH    64
#define NP_   4
#define HH    64
#define WW    64
#define HID   192
#define ROWS  (B_ * LQ)          // 16384
#define EPS_  1e-5f

typedef __bf16 bf16x8 __attribute__((ext_vector_type(8)));
typedef float  f32x4  __attribute__((ext_vector_type(4)));

typedef __attribute__((address_space(3))) void* lds_vp;
typedef const __attribute__((address_space(1))) void* gbl_vp;

// ---------------------------------------------------------------------------
// Weight prep: f32 [K,N] -> bf16 [Npad,K] (transposed); rows n in [N,Npad) zeroed
// ---------------------------------------------------------------------------
__global__ __launch_bounds__(256)
void prep_wt(const float* __restrict__ W, __bf16* __restrict__ Wt,
             int K, int N, int Npad) {
    __shared__ float tile[64][65];
    int k0 = blockIdx.x * 64, n0 = blockIdx.y * 64;
    int c = threadIdx.x & 63, r0 = threadIdx.x >> 6;
    #pragma unroll
    for (int i = 0; i < 16; ++i) {
        int kk = i * 4 + r0;
        float v = 0.f;
        if (k0 + kk < K && n0 + c < N) v = W[(size_t)(k0 + kk) * N + n0 + c];
        tile[kk][c] = v;
    }
    __syncthreads();
    #pragma unroll
    for (int i = 0; i < 16; ++i) {
        int nn = i * 4 + r0;
        if (n0 + nn < Npad && k0 + c < K)
            Wt[(size_t)(n0 + nn) * K + k0 + c] = (__bf16)tile[c][nn];
    }
}

// ---------------------------------------------------------------------------
// LayerNorm: one block (256 thr) per row of C=768 -> bf16 output
// ---------------------------------------------------------------------------
__inline__ __device__ float wave_sum64(float v) {
    #pragma unroll
    for (int o = 32; o > 0; o >>= 1) v += __shfl_down(v, o, 64);
    return v;
}

template <typename T>
__global__ void ln_kernel_bf(const T* __restrict__ x, const float* __restrict__ g,
                             const float* __restrict__ b, __bf16* __restrict__ y, int C) {
    int row = blockIdx.x;
    const T* xr = x + (size_t)row * C;
    __bf16* yr = y + (size_t)row * C;
    float s = 0.f, s2 = 0.f;
    for (int i = threadIdx.x; i < C; i += blockDim.x) {
        float v = (float)xr[i];
        s += v; s2 += v * v;
    }
    __shared__ float red[8];
    float ws = wave_sum64(s), ws2 = wave_sum64(s2);
    int w = threadIdx.x >> 6;
    if ((threadIdx.x & 63) == 0) { red[w] = ws; red[4 + w] = ws2; }
    __syncthreads();
    float S  = red[0] + red[1] + red[2] + red[3];
    float S2 = red[4] + red[5] + red[6] + red[7];
    float mean = S / C;
    float var  = S2 / C - mean * mean;
    float inv  = rsqrtf(var + EPS_);
    for (int i = threadIdx.x; i < C; i += blockDim.x) {
        yr[i] = (__bf16)(((float)xr[i] - mean) * inv * g[i] + b[i]);
    }
}

// ---------------------------------------------------------------------------
// m97-style bf16 MFMA GEMM:
//   A:  bf16 [M,K] row-major; Bt: bf16 [Npad,K] row-major (pre-transposed wt)
//   out[m,n] = act(A[m,:]@Bt[n,:] + bias[n]) + res[m,n], ld = N
// 128x128 tile, BK=32, 256 thr = 4 waves (2x2), 4x4 16x16x32 MFMA per wave.
// Staging via global_load_lds width=16; k-chunk XOR swizzle for 2-way-max
// ds_read_b128 bank aliasing (free per m136).
// flags: 1 = gelu, 2 = out bf16, 4 = res is bf16
// ---------------------------------------------------------------------------
__global__ __launch_bounds__(256)
void gemm_bt(const __bf16* __restrict__ A, const __bf16* __restrict__ Bt,
             const float* __restrict__ ba, int Nsplit, const float* __restrict__ bb,
             const void* __restrict__ res, void* __restrict__ out,
             int M, int K, int N, int flags) {
    __shared__ __bf16 As[128 * 32];
    __shared__ __bf16 Bs[128 * 32];

    int t = threadIdx.x;
    int lane = t & 63, wave = t >> 6;
    int bm = blockIdx.y * 128, bn = blockIdx.x * 128;
    int wm = wave & 1, wn = wave >> 1;

    f32x4 acc[4][4] = {};

    // staging coords for 2 stages of 16B per thread
    int row0 = (0 * 256 + t) >> 2, kc0 = ((0 * 256 + t) & 3) ^ ((row0 >> 1) & 3);
    int row1 = (1 * 256 + t) >> 2, kc1 = ((1 * 256 + t) & 3) ^ ((row1 >> 1) & 3);

    const __bf16* a0 = A  + (size_t)(bm + row0) * K + kc0 * 8;
    const __bf16* a1 = A  + (size_t)(bm + row1) * K + kc1 * 8;
    const __bf16* b0 = Bt + (size_t)(bn + row0) * K + kc0 * 8;
    const __bf16* b1 = Bt + (size_t)(bn + row1) * K + kc1 * 8;

    // fragment read coords
    int rbase = wm * 64 + (lane & 15);
    int nbase = wn * 64 + (lane & 15);
    int kq = lane >> 4;

    for (int k0 = 0; k0 < K; k0 += 32) {
        __syncthreads();    // prior iteration's LDS reads complete
        __builtin_amdgcn_global_load_lds((gbl_vp)(a0 + k0), (lds_vp)&As[(0 * 256 + t) * 8], 16, 0, 0);
        __builtin_amdgcn_global_load_lds((gbl_vp)(a1 + k0), (lds_vp)&As[(1 * 256 + t) * 8], 16, 0, 0);
        __builtin_amdgcn_global_load_lds((gbl_vp)(b0 + k0), (lds_vp)&Bs[(0 * 256 + t) * 8], 16, 0, 0);
        __builtin_amdgcn_global_load_lds((gbl_vp)(b1 + k0), (lds_vp)&Bs[(1 * 256 + t) * 8], 16, 0, 0);
        __syncthreads();    // vmcnt(0) drain: LDS tiles visible

        bf16x8 afr[4], bfr[4];
        #pragma unroll
        for (int i = 0; i < 4; ++i) {
            int r = rbase + i * 16;
            afr[i] = *(const bf16x8*)&As[r * 32 + ((kq ^ ((r >> 1) & 3)) * 8)];
        }
        #pragma unroll
        for (int j = 0; j < 4; ++j) {
            int n = nbase + j * 16;
            bfr[j] = *(const bf16x8*)&Bs[n * 32 + ((kq ^ ((n >> 1) & 3)) * 8)];
        }
        #pragma unroll
        for (int i = 0; i < 4; ++i)
            #pragma unroll
            for (int j = 0; j < 4; ++j)
                acc[i][j] = __builtin_amdgcn_mfma_f32_16x16x32_bf16(afr[i], bfr[j], acc[i][j], 0, 0, 0);
    }

    // epilogue: C/D layout col=lane&15, row=(lane>>4)*4+reg
    int rowq = lane >> 4;
    int colj[4]; float biasj[4];
    #pragma unroll
    for (int j = 0; j < 4; ++j) {
        int c = bn + wn * 64 + j * 16 + (lane & 15);
        colj[j] = c;
        biasj[j] = (c < N) ? ((c < Nsplit) ? ba[c] : bb[c - Nsplit]) : 0.f;
    }
    int do_gelu = flags & 1, out_bf = flags & 2, res_bf = flags & 4;
    #pragma unroll
    for (int i = 0; i < 4; ++i) {
        #pragma unroll
        for (int r = 0; r < 4; ++r) {
            int m = bm + wm * 64 + i * 16 + rowq * 4 + r;
            #pragma unroll
            for (int j = 0; j < 4; ++j) {
                if (colj[j] < N) {
                    float v = acc[i][j][r] + biasj[j];
                    if (do_gelu) v = 0.5f * v * (1.f + erff(v * 0.70710678118f));
                    size_t oi = (size_t)m * N + colj[j];
                    if (res) v += res_bf ? (float)((const __bf16*)res)[oi]
                                         : ((const float*)res)[oi];
                    if (out_bf) ((__bf16*)out)[oi] = (__bf16)v;
                    else        ((float*)out)[oi]  = v;
                }
            }
        }
    }
}

// ---------------------------------------------------------------------------
// Deformable sampling: one wave per (b, q, h); lane = channel dd (0..63).
// value: bf16 [B, Lin, NH*DH]; offatt: f32 [B*Lq, 144]; out: bf16 [B*Lq, C]
// ---------------------------------------------------------------------------
__global__ __launch_bounds__(256)
void sample_kernel(const __bf16* __restrict__ value, const float* __restrict__ offatt,
                   const float* __restrict__ refp, __bf16* __restrict__ out) {
    int wid  = blockIdx.x * (blockDim.x >> 6) + (threadIdx.x >> 6);
    int lane = threadIdx.x & 63;
    int h  = wid % NH_;
    int bq = wid / NH_;

    const float* oa = offatt + (size_t)bq * 144;
    float rx = refp[(size_t)bq * 2 + 0];
    float ry = refp[(size_t)bq * 2 + 1];

    float l0 = oa[96 + h * 4 + 0], l1 = oa[96 + h * 4 + 1];
    float l2 = oa[96 + h * 4 + 2], l3 = oa[96 + h * 4 + 3];
    float mx = fmaxf(fmaxf(l0, l1), fmaxf(l2, l3));
    float e0 = __expf(l0 - mx), e1 = __expf(l1 - mx);
    float e2 = __expf(l2 - mx), e3 = __expf(l3 - mx);
    float rs = 1.f / (e0 + e1 + e2 + e3);
    float wp[4] = {e0 * rs, e1 * rs, e2 * rs, e3 * rs};

    int b = bq / LQ;
    const __bf16* vbase = value + (size_t)b * (LQ * CC) + h * DH + lane;

    float acc = 0.f;
    #pragma unroll
    for (int p = 0; p < NP_; ++p) {
        float ox = oa[h * 8 + p * 2 + 0];
        float oy = oa[h * 8 + p * 2 + 1];
        float x = rx * (float)WW + ox - 0.5f;
        float y = ry * (float)HH + oy - 0.5f;
        float x0f = floorf(x), y0f = floorf(y);
        float wx1 = x - x0f, wy1 = y - y0f;
        float wx0 = 1.f - wx1, wy0 = 1.f - wy1;
        int x0 = (int)x0f, y0 = (int)y0f;
        float sv = 0.f;
        if (x0 >= 0 && x0 < WW && y0 >= 0 && y0 < HH)
            sv += wx0 * wy0 * (float)vbase[(size_t)(y0 * WW + x0) * CC];
        if (x0 + 1 >= 0 && x0 + 1 < WW && y0 >= 0 && y0 < HH)
            sv += wx1 * wy0 * (float)vbase[(size_t)(y0 * WW + x0 + 1) * CC];
        if (x0 >= 0 && x0 < WW && y0 + 1 >= 0 && y0 + 1 < HH)
            sv += wx0 * wy1 * (float)vbase[(size_t)((y0 + 1) * WW + x0) * CC];
        if (x0 + 1 >= 0 && x0 + 1 < WW && y0 + 1 >= 0 && y0 + 1 < HH)
            sv += wx1 * wy1 * (float)vbase[(size_t)((y0 + 1) * WW + x0 + 1) * CC];
        acc += wp[p] * sv;
    }
    out[(size_t)bq * CC + h * DH + lane] = (__bf16)acc;
}

// ---------------------------------------------------------------------------
// Launch
// ---------------------------------------------------------------------------
extern "C" void kernel_launch(void* const* d_in, const int* in_sizes, int n_in,
                              void* d_out, int out_size, void* d_ws, size_t ws_size,
                              hipStream_t stream) {
    const float* query = (const float*)d_in[0];
    const float* refp  = (const float*)d_in[1];
    const float* feat  = (const float*)d_in[2];
    const float* qn_g  = (const float*)d_in[7];
    const float* qn_b  = (const float*)d_in[8];
    const float* fn_g  = (const float*)d_in[9];
    const float* fn_b  = (const float*)d_in[10];
    const float* Wv    = (const float*)d_in[11];
    const float* bv    = (const float*)d_in[12];
    const float* Woff  = (const float*)d_in[13];
    const float* boff  = (const float*)d_in[14];
    const float* Watt  = (const float*)d_in[15];
    const float* batt  = (const float*)d_in[16];
    const float* Wout  = (const float*)d_in[17];
    const float* bout  = (const float*)d_in[18];
    const float* ffn_g = (const float*)d_in[19];
    const float* ffn_b = (const float*)d_in[20];
    const float* W1    = (const float*)d_in[21];
    const float* b1    = (const float*)d_in[22];
    const float* W2    = (const float*)d_in[23];
    const float* b2    = (const float*)d_in[24];
    float* out = (float*)d_out;

    // workspace layout (byte offsets)
    char* ws = (char*)d_ws;
    __bf16* WvT    = (__bf16*)(ws + 0);            // 768x768x2   = 1179648
    __bf16* WcombT = (__bf16*)(ws + 1179648);      // 256x768x2   =  393216
    __bf16* WoutT  = (__bf16*)(ws + 1572864);      // 768x768x2   = 1179648
    __bf16* W1T    = (__bf16*)(ws + 2752512);      // 256x768x2   =  393216
    __bf16* W2T    = (__bf16*)(ws + 3145728);      // 768x192x2   =  294912
    float*  offatt_f = (float*)(ws + 3670016);     // 16384x144x4 = 9437184
    __bf16* h1_bf    = (__bf16*)offatt_f;          // reuse (<= 6291456)
    __bf16* bufA     = (__bf16*)(ws + 13107200);   // 16384x768x2 = 25165824
    __bf16* qn_bf    = bufA;                       // dead after offatt GEMM
    __bf16* value_bf = bufA;                       // written step 4
    __bf16* bufB     = (__bf16*)(ws + 38273024);   // 25165824
    __bf16* fn_bf    = bufB;                       // dead after step 4
    __bf16* samp_bf  = bufB;                       // written step 5
    __bf16* h_bf     = bufB;                       // written step 7
    __bf16* attn_bf  = (__bf16*)(ws + 63438848);   // 25165824

    dim3 blk(256);

    // 0. weight prep (transpose + bf16; pad rows zeroed)
    prep_wt<<<dim3(12, 12), blk, 0, stream>>>(Wv,   WvT,             768, 768, 768);
    prep_wt<<<dim3(12,  2), blk, 0, stream>>>(Woff, WcombT,          768,  96,  96);
    prep_wt<<<dim3(12,  3), blk, 0, stream>>>(Watt, WcombT + 96*768, 768,  48, 160);
    prep_wt<<<dim3(12, 12), blk, 0, stream>>>(Wout, WoutT,           768, 768, 768);
    prep_wt<<<dim3(12,  4), blk, 0, stream>>>(W1,   W1T,             768, 192, 256);
    prep_wt<<<dim3( 3, 12), blk, 0, stream>>>(W2,   W2T,             192, 768, 768);

    // 1-2. LayerNorms -> bf16
    ln_kernel_bf<float><<<ROWS, blk, 0, stream>>>(query, qn_g, qn_b, qn_bf, CC);
    ln_kernel_bf<float><<<ROWS, blk, 0, stream>>>(feat,  fn_g, fn_b, fn_bf, CC);

    // 3. offatt = qn @ [Woff|Watt] + [boff|batt]  (N=144, f32 out)
    gemm_bt<<<dim3(2, ROWS / 128), blk, 0, stream>>>(
        qn_bf, WcombT, boff, 96, batt, nullptr, offatt_f, ROWS, CC, 144, 0);
    // 4. value = fn @ Wv + bv (bf16 out)  [overwrites qn region]
    gemm_bt<<<dim3(6, ROWS / 128), blk, 0, stream>>>(
        fn_bf, WvT, bv, CC, nullptr, nullptr, value_bf, ROWS, CC, CC, 2);
    // 5. deformable sampling -> bf16 [overwrites fn region]
    sample_kernel<<<ROWS * NH_ / 4, blk, 0, stream>>>(value_bf, offatt_f, refp, samp_bf);
    // 6. attnres = query + samp @ Wout + bout (bf16 out)
    gemm_bt<<<dim3(6, ROWS / 128), blk, 0, stream>>>(
        samp_bf, WoutT, bout, CC, nullptr, query, attn_bf, ROWS, CC, CC, 2);
    // 7. h = LN(attnres) -> bf16
    ln_kernel_bf<__bf16><<<ROWS, blk, 0, stream>>>(attn_bf, ffn_g, ffn_b, h_bf, CC);
    // 8. h1 = gelu(h @ W1 + b1) -> bf16 (N=192)
    gemm_bt<<<dim3(2, ROWS / 128), blk, 0, stream>>>(
        h_bf, W1T, b1, HID, nullptr, nullptr, h1_bf, ROWS, CC, HID, 1 | 2);
    // 9. out = attnres + h1 @ W2 + b2 (K=192, f32 out, bf16 res)
    gemm_bt<<<dim3(6, ROWS / 128), blk, 0, stream>>>(
        h1_bf, W2T, b2, CC, nullptr, attn_bf, out, ROWS, HID, CC, 4);
}

// Round 4
// 585.881 us; speedup vs baseline: 2.5301x; 1.1646x over previous
//
#include <hip/hip_runtime.h>
#include <hip/hip_bf16.h>
#include <math.h>

// Problem constants:
//   B=4, Lq=4096, C=768, NH=12, d=64, NP=4, nl=1, H=W=64, Lin=4096, hid=192
#define B_    4
#define LQ    4096
#define CC    768
#define NH_   12
#define DH    64
#define NP_   4
#define HH    64
#define WW    64
#define HID   192
#define ROWS  (B_ * LQ)          // 16384
#define EPS_  1e-5f

typedef __bf16 bf16x8 __attribute__((ext_vector_type(8)));
typedef __bf16 bf16x4 __attribute__((ext_vector_type(4)));
typedef float  f32x4  __attribute__((ext_vector_type(4)));

typedef __attribute__((address_space(3))) void* lds_vp;
typedef const __attribute__((address_space(1))) void* gbl_vp;

// ---------------------------------------------------------------------------
// Weight prep: f32 [K,N] -> bf16 [Npad,K] (transposed); rows n in [N,Npad) zeroed
// ---------------------------------------------------------------------------
__global__ __launch_bounds__(256)
void prep_wt(const float* __restrict__ W, __bf16* __restrict__ Wt,
             int K, int N, int Npad) {
    __shared__ float tile[64][65];
    int k0 = blockIdx.x * 64, n0 = blockIdx.y * 64;
    int c = threadIdx.x & 63, r0 = threadIdx.x >> 6;
    #pragma unroll
    for (int i = 0; i < 16; ++i) {
        int kk = i * 4 + r0;
        float v = 0.f;
        if (k0 + kk < K && n0 + c < N) v = W[(size_t)(k0 + kk) * N + n0 + c];
        tile[kk][c] = v;
    }
    __syncthreads();
    #pragma unroll
    for (int i = 0; i < 16; ++i) {
        int nn = i * 4 + r0;
        if (n0 + nn < Npad && k0 + c < K)
            Wt[(size_t)(n0 + nn) * K + k0 + c] = (__bf16)tile[c][nn];
    }
}

// ---------------------------------------------------------------------------
// LayerNorm: one block (256 thr) per row of C=768 -> bf16 output
// ---------------------------------------------------------------------------
__inline__ __device__ float wave_sum64(float v) {
    #pragma unroll
    for (int o = 32; o > 0; o >>= 1) v += __shfl_down(v, o, 64);
    return v;
}

template <typename T>
__global__ void ln_kernel_bf(const T* __restrict__ x, const float* __restrict__ g,
                             const float* __restrict__ b, __bf16* __restrict__ y, int C) {
    int row = blockIdx.x;
    const T* xr = x + (size_t)row * C;
    __bf16* yr = y + (size_t)row * C;
    float s = 0.f, s2 = 0.f;
    for (int i = threadIdx.x; i < C; i += blockDim.x) {
        float v = (float)xr[i];
        s += v; s2 += v * v;
    }
    __shared__ float red[8];
    float ws = wave_sum64(s), ws2 = wave_sum64(s2);
    int w = threadIdx.x >> 6;
    if ((threadIdx.x & 63) == 0) { red[w] = ws; red[4 + w] = ws2; }
    __syncthreads();
    float S  = red[0] + red[1] + red[2] + red[3];
    float S2 = red[4] + red[5] + red[6] + red[7];
    float mean = S / C;
    float var  = S2 / C - mean * mean;
    float inv  = rsqrtf(var + EPS_);
    for (int i = threadIdx.x; i < C; i += blockDim.x) {
        yr[i] = (__bf16)(((float)xr[i] - mean) * inv * g[i] + b[i]);
    }
}

// ---------------------------------------------------------------------------
// m97-style bf16 MFMA GEMM (unchanged from R3)
// flags: 1 = gelu, 2 = out bf16, 4 = res is bf16
// ---------------------------------------------------------------------------
__global__ __launch_bounds__(256)
void gemm_bt(const __bf16* __restrict__ A, const __bf16* __restrict__ Bt,
             const float* __restrict__ ba, int Nsplit, const float* __restrict__ bb,
             const void* __restrict__ res, void* __restrict__ out,
             int M, int K, int N, int flags) {
    __shared__ __bf16 As[128 * 32];
    __shared__ __bf16 Bs[128 * 32];

    int t = threadIdx.x;
    int lane = t & 63, wave = t >> 6;
    int bm = blockIdx.y * 128, bn = blockIdx.x * 128;
    int wm = wave & 1, wn = wave >> 1;

    f32x4 acc[4][4] = {};

    int row0 = (0 * 256 + t) >> 2, kc0 = ((0 * 256 + t) & 3) ^ ((row0 >> 1) & 3);
    int row1 = (1 * 256 + t) >> 2, kc1 = ((1 * 256 + t) & 3) ^ ((row1 >> 1) & 3);

    const __bf16* a0 = A  + (size_t)(bm + row0) * K + kc0 * 8;
    const __bf16* a1 = A  + (size_t)(bm + row1) * K + kc1 * 8;
    const __bf16* b0 = Bt + (size_t)(bn + row0) * K + kc0 * 8;
    const __bf16* b1 = Bt + (size_t)(bn + row1) * K + kc1 * 8;

    int rbase = wm * 64 + (lane & 15);
    int nbase = wn * 64 + (lane & 15);
    int kq = lane >> 4;

    for (int k0 = 0; k0 < K; k0 += 32) {
        __syncthreads();
        __builtin_amdgcn_global_load_lds((gbl_vp)(a0 + k0), (lds_vp)&As[(0 * 256 + t) * 8], 16, 0, 0);
        __builtin_amdgcn_global_load_lds((gbl_vp)(a1 + k0), (lds_vp)&As[(1 * 256 + t) * 8], 16, 0, 0);
        __builtin_amdgcn_global_load_lds((gbl_vp)(b0 + k0), (lds_vp)&Bs[(0 * 256 + t) * 8], 16, 0, 0);
        __builtin_amdgcn_global_load_lds((gbl_vp)(b1 + k0), (lds_vp)&Bs[(1 * 256 + t) * 8], 16, 0, 0);
        __syncthreads();

        bf16x8 afr[4], bfr[4];
        #pragma unroll
        for (int i = 0; i < 4; ++i) {
            int r = rbase + i * 16;
            afr[i] = *(const bf16x8*)&As[r * 32 + ((kq ^ ((r >> 1) & 3)) * 8)];
        }
        #pragma unroll
        for (int j = 0; j < 4; ++j) {
            int n = nbase + j * 16;
            bfr[j] = *(const bf16x8*)&Bs[n * 32 + ((kq ^ ((n >> 1) & 3)) * 8)];
        }
        #pragma unroll
        for (int i = 0; i < 4; ++i)
            #pragma unroll
            for (int j = 0; j < 4; ++j)
                acc[i][j] = __builtin_amdgcn_mfma_f32_16x16x32_bf16(afr[i], bfr[j], acc[i][j], 0, 0, 0);
    }

    int rowq = lane >> 4;
    int colj[4]; float biasj[4];
    #pragma unroll
    for (int j = 0; j < 4; ++j) {
        int c = bn + wn * 64 + j * 16 + (lane & 15);
        colj[j] = c;
        biasj[j] = (c < N) ? ((c < Nsplit) ? ba[c] : bb[c - Nsplit]) : 0.f;
    }
    int do_gelu = flags & 1, out_bf = flags & 2, res_bf = flags & 4;
    #pragma unroll
    for (int i = 0; i < 4; ++i) {
        #pragma unroll
        for (int r = 0; r < 4; ++r) {
            int m = bm + wm * 64 + i * 16 + rowq * 4 + r;
            #pragma unroll
            for (int j = 0; j < 4; ++j) {
                if (colj[j] < N) {
                    float v = acc[i][j][r] + biasj[j];
                    if (do_gelu) v = 0.5f * v * (1.f + erff(v * 0.70710678118f));
                    size_t oi = (size_t)m * N + colj[j];
                    if (res) v += res_bf ? (float)((const __bf16*)res)[oi]
                                         : ((const float*)res)[oi];
                    if (out_bf) ((__bf16*)out)[oi] = (__bf16)v;
                    else        ((float*)out)[oi]  = v;
                }
            }
        }
    }
}

// ---------------------------------------------------------------------------
// Deformable sampling v2: one wave per (b, q, h).
//   lane = c*16 + g:  c = corner (0..3: {x0,y0},{x1,y0},{x0,y1},{x1,y1}),
//                     g = channel group (4 bf16 channels per lane).
// One bf16x4 gather per lane per point -> all 4 corners in ONE wave-load.
// Butterfly (xor 16,32) sums corners; lanes c==0 store bf16x4 (128 B/ (q,h)).
// ---------------------------------------------------------------------------
__global__ __launch_bounds__(256)
void sample_kernel(const __bf16* __restrict__ value, const float* __restrict__ offatt,
                   const float* __restrict__ refp, __bf16* __restrict__ out) {
    int wid  = blockIdx.x * 4 + (threadIdx.x >> 6);
    int lane = threadIdx.x & 63;
    int h  = wid % NH_;
    int bq = wid / NH_;
    int b  = bq / LQ;

    const float* oa = offatt + (size_t)bq * 144;
    float rx = refp[(size_t)bq * 2 + 0] * (float)WW - 0.5f;
    float ry = refp[(size_t)bq * 2 + 1] * (float)HH - 0.5f;

    // softmax over the 4 attention logits of this head
    float l0 = oa[96 + h * 4 + 0], l1 = oa[96 + h * 4 + 1];
    float l2 = oa[96 + h * 4 + 2], l3 = oa[96 + h * 4 + 3];
    float mx = fmaxf(fmaxf(l0, l1), fmaxf(l2, l3));
    float e0 = __expf(l0 - mx), e1 = __expf(l1 - mx);
    float e2 = __expf(l2 - mx), e3 = __expf(l3 - mx);
    float rs = 1.f / (e0 + e1 + e2 + e3);
    float wp[4] = {e0 * rs, e1 * rs, e2 * rs, e3 * rs};

    int c = lane >> 4;        // corner id
    int g = lane & 15;        // channel group
    int cx = c & 1, cy = c >> 1;
    const __bf16* vbase = value + (size_t)b * (LQ * CC) + h * DH + g * 4;

    f32x4 acc = {0.f, 0.f, 0.f, 0.f};
    #pragma unroll
    for (int p = 0; p < NP_; ++p) {
        float x = rx + oa[h * 8 + p * 2 + 0];
        float y = ry + oa[h * 8 + p * 2 + 1];
        float x0f = floorf(x), y0f = floorf(y);
        float wx1 = x - x0f, wy1 = y - y0f;
        int x0 = (int)x0f, y0 = (int)y0f;
        int xi = x0 + cx, yi = y0 + cy;
        float wgt = (cx ? wx1 : 1.f - wx1) * (cy ? wy1 : 1.f - wy1) * wp[p];
        bool valid = (xi >= 0) & (xi < WW) & (yi >= 0) & (yi < HH);
        wgt = valid ? wgt : 0.f;
        int xc = min(max(xi, 0), WW - 1), yc = min(max(yi, 0), HH - 1);
        bf16x4 v = *(const bf16x4*)(vbase + (size_t)(yc * WW + xc) * CC);
        acc[0] += wgt * (float)v[0];
        acc[1] += wgt * (float)v[1];
        acc[2] += wgt * (float)v[2];
        acc[3] += wgt * (float)v[3];
    }
    // reduce across the 4 corner groups (lanes xor 16, 32)
    #pragma unroll
    for (int e = 0; e < 4; ++e) {
        acc[e] += __shfl_xor(acc[e], 16, 64);
        acc[e] += __shfl_xor(acc[e], 32, 64);
    }
    if (c == 0) {
        bf16x4 o;
        o[0] = (__bf16)acc[0]; o[1] = (__bf16)acc[1];
        o[2] = (__bf16)acc[2]; o[3] = (__bf16)acc[3];
        *(bf16x4*)(out + (size_t)bq * CC + h * DH + g * 4) = o;
    }
}

// ---------------------------------------------------------------------------
// Launch
// ---------------------------------------------------------------------------
extern "C" void kernel_launch(void* const* d_in, const int* in_sizes, int n_in,
                              void* d_out, int out_size, void* d_ws, size_t ws_size,
                              hipStream_t stream) {
    const float* query = (const float*)d_in[0];
    const float* refp  = (const float*)d_in[1];
    const float* feat  = (const float*)d_in[2];
    const float* qn_g  = (const float*)d_in[7];
    const float* qn_b  = (const float*)d_in[8];
    const float* fn_g  = (const float*)d_in[9];
    const float* fn_b  = (const float*)d_in[10];
    const float* Wv    = (const float*)d_in[11];
    const float* bv    = (const float*)d_in[12];
    const float* Woff  = (const float*)d_in[13];
    const float* boff  = (const float*)d_in[14];
    const float* Watt  = (const float*)d_in[15];
    const float* batt  = (const float*)d_in[16];
    const float* Wout  = (const float*)d_in[17];
    const float* bout  = (const float*)d_in[18];
    const float* ffn_g = (const float*)d_in[19];
    const float* ffn_b = (const float*)d_in[20];
    const float* W1    = (const float*)d_in[21];
    const float* b1    = (const float*)d_in[22];
    const float* W2    = (const float*)d_in[23];
    const float* b2    = (const float*)d_in[24];
    float* out = (float*)d_out;

    // workspace layout (byte offsets)
    char* ws = (char*)d_ws;
    __bf16* WvT    = (__bf16*)(ws + 0);            // 1179648
    __bf16* WcombT = (__bf16*)(ws + 1179648);      //  393216
    __bf16* WoutT  = (__bf16*)(ws + 1572864);      // 1179648
    __bf16* W1T    = (__bf16*)(ws + 2752512);      //  393216
    __bf16* W2T    = (__bf16*)(ws + 3145728);      //  294912
    float*  offatt_f = (float*)(ws + 3670016);     // 9437184
    __bf16* h1_bf    = (__bf16*)offatt_f;          // reuse
    __bf16* bufA     = (__bf16*)(ws + 13107200);   // 25165824
    __bf16* qn_bf    = bufA;
    __bf16* value_bf = bufA;
    __bf16* bufB     = (__bf16*)(ws + 38273024);   // 25165824
    __bf16* fn_bf    = bufB;
    __bf16* samp_bf  = bufB;
    __bf16* h_bf     = bufB;
    __bf16* attn_bf  = (__bf16*)(ws + 63438848);   // 25165824

    dim3 blk(256);

    // 0. weight prep
    prep_wt<<<dim3(12, 12), blk, 0, stream>>>(Wv,   WvT,             768, 768, 768);
    prep_wt<<<dim3(12,  2), blk, 0, stream>>>(Woff, WcombT,          768,  96,  96);
    prep_wt<<<dim3(12,  3), blk, 0, stream>>>(Watt, WcombT + 96*768, 768,  48, 160);
    prep_wt<<<dim3(12, 12), blk, 0, stream>>>(Wout, WoutT,           768, 768, 768);
    prep_wt<<<dim3(12,  4), blk, 0, stream>>>(W1,   W1T,             768, 192, 256);
    prep_wt<<<dim3( 3, 12), blk, 0, stream>>>(W2,   W2T,             192, 768, 768);

    // 1-2. LayerNorms -> bf16
    ln_kernel_bf<float><<<ROWS, blk, 0, stream>>>(query, qn_g, qn_b, qn_bf, CC);
    ln_kernel_bf<float><<<ROWS, blk, 0, stream>>>(feat,  fn_g, fn_b, fn_bf, CC);

    // 3. offatt = qn @ [Woff|Watt] + [boff|batt]  (N=144, f32 out)
    gemm_bt<<<dim3(2, ROWS / 128), blk, 0, stream>>>(
        qn_bf, WcombT, boff, 96, batt, nullptr, offatt_f, ROWS, CC, 144, 0);
    // 4. value = fn @ Wv + bv (bf16 out)
    gemm_bt<<<dim3(6, ROWS / 128), blk, 0, stream>>>(
        fn_bf, WvT, bv, CC, nullptr, nullptr, value_bf, ROWS, CC, CC, 2);
    // 5. deformable sampling -> bf16
    sample_kernel<<<ROWS * NH_ / 4, blk, 0, stream>>>(value_bf, offatt_f, refp, samp_bf);
    // 6. attnres = query + samp @ Wout + bout (bf16 out)
    gemm_bt<<<dim3(6, ROWS / 128), blk, 0, stream>>>(
        samp_bf, WoutT, bout, CC, nullptr, query, attn_bf, ROWS, CC, CC, 2);
    // 7. h = LN(attnres) -> bf16
    ln_kernel_bf<__bf16><<<ROWS, blk, 0, stream>>>(attn_bf, ffn_g, ffn_b, h_bf, CC);
    // 8. h1 = gelu(h @ W1 + b1) -> bf16 (N=192)
    gemm_bt<<<dim3(2, ROWS / 128), blk, 0, stream>>>(
        h_bf, W1T, b1, HID, nullptr, nullptr, h1_bf, ROWS, CC, HID, 1 | 2);
    // 9. out = attnres + h1 @ W2 + b2 (K=192, f32 out, bf16 res)
    gemm_bt<<<dim3(6, ROWS / 128), blk, 0, stream>>>(
        h1_bf, W2T, b2, CC, nullptr, attn_bf, out, ROWS, HID, CC, 4);
}

// Round 5
// 450.111 us; speedup vs baseline: 3.2932x; 1.3016x over previous
//
#include <hip/hip_runtime.h>
#include <hip/hip_bf16.h>
#include <math.h>

// Problem constants:
//   B=4, Lq=4096, C=768, NH=12, d=64, NP=4, nl=1, H=W=64, Lin=4096, hid=192
#define B_    4
#define LQ    4096
#define CC    768
#define NH_   12
#define DH    64
#define NP_   4
#define HH    64
#define WW    64
#define HID   192
#define ROWS  (B_ * LQ)          // 16384
#define EPS_  1e-5f

typedef __bf16 bf16x8 __attribute__((ext_vector_type(8)));
typedef __bf16 bf16x4 __attribute__((ext_vector_type(4)));
typedef float  f32x4  __attribute__((ext_vector_type(4)));

typedef __attribute__((address_space(3))) void* lds_vp;
typedef const __attribute__((address_space(1))) void* gbl_vp;

// ---------------------------------------------------------------------------
// Batched weight prep: f32 [K,N] -> bf16 [Npad,K] transposed; rows [N,Npad) zero
// ---------------------------------------------------------------------------
struct PrepJob { const float* W; __bf16* Wt; int K; int N; int Npad; };
struct PrepJobs { PrepJob j[6]; };

__global__ __launch_bounds__(256)
void prep_all(PrepJobs jobs) {
    PrepJob job = jobs.j[blockIdx.z];
    int k0 = blockIdx.x * 64, n0 = blockIdx.y * 64;
    if (k0 >= job.K || n0 >= job.Npad) return;
    __shared__ float tile[64][65];
    int c = threadIdx.x & 63, r0 = threadIdx.x >> 6;
    #pragma unroll
    for (int i = 0; i < 16; ++i) {
        int kk = i * 4 + r0;
        float v = 0.f;
        if (k0 + kk < job.K && n0 + c < job.N) v = job.W[(size_t)(k0 + kk) * job.N + n0 + c];
        tile[kk][c] = v;
    }
    __syncthreads();
    #pragma unroll
    for (int i = 0; i < 16; ++i) {
        int nn = i * 4 + r0;
        if (n0 + nn < job.Npad && k0 + c < job.K)
            job.Wt[(size_t)(n0 + nn) * job.K + k0 + c] = (__bf16)tile[c][nn];
    }
}

// ---------------------------------------------------------------------------
// Reductions
// ---------------------------------------------------------------------------
__inline__ __device__ float wave_sum64(float v) {
    #pragma unroll
    for (int o = 32; o > 0; o >>= 1) v += __shfl_down(v, o, 64);
    return v;
}

// ---------------------------------------------------------------------------
// Fused dual LayerNorm (f32 in, bf16 out), float4 vectorized.
// blockIdx.y selects stream 0 (query) or 1 (feat). 256 thr, 192 active vec4.
// ---------------------------------------------------------------------------
__global__ __launch_bounds__(256)
void ln2_kernel(const float* __restrict__ x0, const float* __restrict__ g0,
                const float* __restrict__ b0, __bf16* __restrict__ y0,
                const float* __restrict__ x1, const float* __restrict__ g1,
                const float* __restrict__ b1, __bf16* __restrict__ y1) {
    int sel = blockIdx.y;
    const float* x = sel ? x1 : x0;
    const float* g = sel ? g1 : g0;
    const float* b = sel ? b1 : b0;
    __bf16* y = sel ? y1 : y0;
    int row = blockIdx.x;
    const float* xr = x + (size_t)row * CC;
    __bf16* yr = y + (size_t)row * CC;
    int t = threadIdx.x;
    f32x4 xv = {0.f, 0.f, 0.f, 0.f};
    if (t < 192) xv = *(const f32x4*)(xr + t * 4);
    float s  = xv[0] + xv[1] + xv[2] + xv[3];
    float s2 = xv[0]*xv[0] + xv[1]*xv[1] + xv[2]*xv[2] + xv[3]*xv[3];
    __shared__ float red[8];
    float ws = wave_sum64(s), ws2 = wave_sum64(s2);
    int w = t >> 6;
    if ((t & 63) == 0) { red[w] = ws; red[4 + w] = ws2; }
    __syncthreads();
    float S  = red[0] + red[1] + red[2] + red[3];
    float S2 = red[4] + red[5] + red[6] + red[7];
    float mean = S / CC;
    float inv  = rsqrtf(S2 / CC - mean * mean + EPS_);
    if (t < 192) {
        f32x4 gv = *(const f32x4*)(g + t * 4);
        f32x4 bv = *(const f32x4*)(b + t * 4);
        bf16x4 o;
        #pragma unroll
        for (int e = 0; e < 4; ++e)
            o[e] = (__bf16)((xv[e] - mean) * inv * gv[e] + bv[e]);
        *(bf16x4*)(yr + t * 4) = o;
    }
}

// ---------------------------------------------------------------------------
// LayerNorm, bf16 in -> bf16 out, bf16x8 vectorized (96 active threads of 256)
// ---------------------------------------------------------------------------
__global__ __launch_bounds__(256)
void ln_bf_kernel(const __bf16* __restrict__ x, const float* __restrict__ g,
                  const float* __restrict__ b, __bf16* __restrict__ y) {
    int row = blockIdx.x;
    const __bf16* xr = x + (size_t)row * CC;
    __bf16* yr = y + (size_t)row * CC;
    int t = threadIdx.x;
    float xv[8]; bf16x8 raw = {};
    if (t < 96) raw = *(const bf16x8*)(xr + t * 8);
    float s = 0.f, s2 = 0.f;
    #pragma unroll
    for (int e = 0; e < 8; ++e) { xv[e] = (float)raw[e]; s += xv[e]; s2 += xv[e]*xv[e]; }
    __shared__ float red[8];
    float ws = wave_sum64(s), ws2 = wave_sum64(s2);
    int w = t >> 6;
    if ((t & 63) == 0) { red[w] = ws; red[4 + w] = ws2; }
    __syncthreads();
    float S  = red[0] + red[1] + red[2] + red[3];
    float S2 = red[4] + red[5] + red[6] + red[7];
    float mean = S / CC;
    float inv  = rsqrtf(S2 / CC - mean * mean + EPS_);
    if (t < 96) {
        bf16x8 o;
        #pragma unroll
        for (int e = 0; e < 8; ++e)
            o[e] = (__bf16)((xv[e] - mean) * inv * g[t * 8 + e] + b[t * 8 + e]);
        *(bf16x8*)(yr + t * 8) = o;
    }
}

// ---------------------------------------------------------------------------
// m97-style bf16 MFMA GEMM, 128x128 tile (big N). flags: 1 gelu, 2 out bf16, 4 res bf16
// ---------------------------------------------------------------------------
__global__ __launch_bounds__(256)
void gemm_bt(const __bf16* __restrict__ A, const __bf16* __restrict__ Bt,
             const float* __restrict__ ba, int Nsplit, const float* __restrict__ bb,
             const void* __restrict__ res, void* __restrict__ out,
             int M, int K, int N, int flags) {
    __shared__ __bf16 As[128 * 32];
    __shared__ __bf16 Bs[128 * 32];

    int t = threadIdx.x;
    int lane = t & 63, wave = t >> 6;
    int bm = blockIdx.y * 128, bn = blockIdx.x * 128;
    int wm = wave & 1, wn = wave >> 1;

    f32x4 acc[4][4] = {};

    int row0 = t >> 2,           kc0 = (t & 3) ^ ((row0 >> 1) & 3);
    int row1 = (256 + t) >> 2,   kc1 = ((256 + t) & 3) ^ ((row1 >> 1) & 3);

    const __bf16* a0 = A  + (size_t)(bm + row0) * K + kc0 * 8;
    const __bf16* a1 = A  + (size_t)(bm + row1) * K + kc1 * 8;
    const __bf16* b0 = Bt + (size_t)(bn + row0) * K + kc0 * 8;
    const __bf16* b1 = Bt + (size_t)(bn + row1) * K + kc1 * 8;

    int rbase = wm * 64 + (lane & 15);
    int nbase = wn * 64 + (lane & 15);
    int kq = lane >> 4;

    for (int k0 = 0; k0 < K; k0 += 32) {
        __syncthreads();
        __builtin_amdgcn_global_load_lds((gbl_vp)(a0 + k0), (lds_vp)&As[t * 8], 16, 0, 0);
        __builtin_amdgcn_global_load_lds((gbl_vp)(a1 + k0), (lds_vp)&As[(256 + t) * 8], 16, 0, 0);
        __builtin_amdgcn_global_load_lds((gbl_vp)(b0 + k0), (lds_vp)&Bs[t * 8], 16, 0, 0);
        __builtin_amdgcn_global_load_lds((gbl_vp)(b1 + k0), (lds_vp)&Bs[(256 + t) * 8], 16, 0, 0);
        __syncthreads();

        bf16x8 afr[4], bfr[4];
        #pragma unroll
        for (int i = 0; i < 4; ++i) {
            int r = rbase + i * 16;
            afr[i] = *(const bf16x8*)&As[r * 32 + ((kq ^ ((r >> 1) & 3)) * 8)];
        }
        #pragma unroll
        for (int j = 0; j < 4; ++j) {
            int n = nbase + j * 16;
            bfr[j] = *(const bf16x8*)&Bs[n * 32 + ((kq ^ ((n >> 1) & 3)) * 8)];
        }
        #pragma unroll
        for (int i = 0; i < 4; ++i)
            #pragma unroll
            for (int j = 0; j < 4; ++j)
                acc[i][j] = __builtin_amdgcn_mfma_f32_16x16x32_bf16(afr[i], bfr[j], acc[i][j], 0, 0, 0);
    }

    int rowq = lane >> 4;
    int colj[4]; float biasj[4];
    #pragma unroll
    for (int j = 0; j < 4; ++j) {
        int c = bn + wn * 64 + j * 16 + (lane & 15);
        colj[j] = c;
        biasj[j] = (c < N) ? ((c < Nsplit) ? ba[c] : bb[c - Nsplit]) : 0.f;
    }
    int do_gelu = flags & 1, out_bf = flags & 2, res_bf = flags & 4;
    #pragma unroll
    for (int i = 0; i < 4; ++i) {
        #pragma unroll
        for (int r = 0; r < 4; ++r) {
            int m = bm + wm * 64 + i * 16 + rowq * 4 + r;
            #pragma unroll
            for (int j = 0; j < 4; ++j) {
                if (colj[j] < N) {
                    float v = acc[i][j][r] + biasj[j];
                    if (do_gelu) v = 0.5f * v * (1.f + erff(v * 0.70710678118f));
                    size_t oi = (size_t)m * N + colj[j];
                    if (res) v += res_bf ? (float)((const __bf16*)res)[oi]
                                         : ((const float*)res)[oi];
                    if (out_bf) ((__bf16*)out)[oi] = (__bf16)v;
                    else        ((float*)out)[oi]  = v;
                }
            }
        }
    }
}

// ---------------------------------------------------------------------------
// 64x64-tile GEMM for small N (144/192): 4 waves, wave w = rows [w*16, w*16+16)
// Grid: (Npad/64, M/64). Same staging style, 4 MFMA/iter/wave.
// flags: 1 gelu, 2 out bf16
// ---------------------------------------------------------------------------
__global__ __launch_bounds__(256)
void gemm_bt64(const __bf16* __restrict__ A, const __bf16* __restrict__ Bt,
               const float* __restrict__ ba, int Nsplit, const float* __restrict__ bb,
               void* __restrict__ out, int M, int K, int N, int flags) {
    __shared__ __bf16 As[64 * 32];
    __shared__ __bf16 Bs[64 * 32];

    int t = threadIdx.x;
    int lane = t & 63, wave = t >> 6;
    int bm = blockIdx.y * 64, bn = blockIdx.x * 64;

    f32x4 acc[4] = {};

    int row0 = t >> 2, kc0 = (t & 3) ^ ((row0 >> 1) & 3);
    const __bf16* a0 = A  + (size_t)(bm + row0) * K + kc0 * 8;
    const __bf16* b0 = Bt + (size_t)(bn + row0) * K + kc0 * 8;

    int rbase = wave * 16 + (lane & 15);
    int nbase = lane & 15;
    int kq = lane >> 4;

    for (int k0 = 0; k0 < K; k0 += 32) {
        __syncthreads();
        __builtin_amdgcn_global_load_lds((gbl_vp)(a0 + k0), (lds_vp)&As[t * 8], 16, 0, 0);
        __builtin_amdgcn_global_load_lds((gbl_vp)(b0 + k0), (lds_vp)&Bs[t * 8], 16, 0, 0);
        __syncthreads();

        bf16x8 afr = *(const bf16x8*)&As[rbase * 32 + ((kq ^ ((rbase >> 1) & 3)) * 8)];
        #pragma unroll
        for (int j = 0; j < 4; ++j) {
            int n = nbase + j * 16;
            bf16x8 bfr = *(const bf16x8*)&Bs[n * 32 + ((kq ^ ((n >> 1) & 3)) * 8)];
            acc[j] = __builtin_amdgcn_mfma_f32_16x16x32_bf16(afr, bfr, acc[j], 0, 0, 0);
        }
    }

    int rowq = lane >> 4;
    int do_gelu = flags & 1, out_bf = flags & 2;
    #pragma unroll
    for (int r = 0; r < 4; ++r) {
        int m = bm + wave * 16 + rowq * 4 + r;
        #pragma unroll
        for (int j = 0; j < 4; ++j) {
            int c = bn + j * 16 + (lane & 15);
            if (c < N) {
                float v = acc[j][r] + ((c < Nsplit) ? ba[c] : bb[c - Nsplit]);
                if (do_gelu) v = 0.5f * v * (1.f + erff(v * 0.70710678118f));
                size_t oi = (size_t)m * N + c;
                if (out_bf) ((__bf16*)out)[oi] = (__bf16)v;
                else        ((float*)out)[oi]  = v;
            }
        }
    }
}

// ---------------------------------------------------------------------------
// Deformable sampling v3: one wave per (b,q,h).
//   lane = p*16 + g : p = sample point (0..3), g = channel group (4 bf16).
// Each lane: one coord chain, 4 in-lane corner loads (constant cx/cy).
// Butterfly (xor 16,32) sums points; lanes p==0 store bf16x4.
// ---------------------------------------------------------------------------
__global__ __launch_bounds__(256)
void sample_kernel(const __bf16* __restrict__ value, const float* __restrict__ offatt,
                   const float* __restrict__ refp, __bf16* __restrict__ out) {
    int wid  = blockIdx.x * 4 + (threadIdx.x >> 6);
    int lane = threadIdx.x & 63;
    int h  = wid % NH_;
    int bq = wid / NH_;
    int b  = bq / LQ;

    const float* oa = offatt + (size_t)bq * 144;
    float rx = refp[(size_t)bq * 2 + 0] * (float)WW - 0.5f;
    float ry = refp[(size_t)bq * 2 + 1] * (float)HH - 0.5f;

    // softmax over this head's 4 logits (wave-uniform -> s_loads)
    float l0 = oa[96 + h * 4 + 0], l1 = oa[96 + h * 4 + 1];
    float l2 = oa[96 + h * 4 + 2], l3 = oa[96 + h * 4 + 3];
    float mx = fmaxf(fmaxf(l0, l1), fmaxf(l2, l3));
    float e0 = __expf(l0 - mx), e1 = __expf(l1 - mx);
    float e2 = __expf(l2 - mx), e3 = __expf(l3 - mx);
    float rs = 1.f / (e0 + e1 + e2 + e3);

    int pp = lane >> 4;       // point id
    int g  = lane & 15;       // channel group
    float wpl = (pp == 0) ? e0 : (pp == 1) ? e1 : (pp == 2) ? e2 : e3;
    wpl *= rs;

    // per-lane point coords (8B vector load, divergent by pp)
    const float* oxy = oa + h * 8 + pp * 2;
    float x = rx + oxy[0];
    float y = ry + oxy[1];
    float x0f = floorf(x), y0f = floorf(y);
    float wx1 = x - x0f, wy1 = y - y0f;
    float wx0 = 1.f - wx1, wy0 = 1.f - wy1;
    int x0 = (int)x0f, y0 = (int)y0f;
    int x1 = x0 + 1, y1 = y0 + 1;
    // zero weights at OOB; address clamp via &63 (weight already 0 there)
    float mx0 = ((unsigned)x0 < (unsigned)WW) ? wx0 : 0.f;
    float mx1 = ((unsigned)x1 < (unsigned)WW) ? wx1 : 0.f;
    float my0 = (((unsigned)y0 < (unsigned)HH) ? wy0 : 0.f) * wpl;
    float my1 = (((unsigned)y1 < (unsigned)HH) ? wy1 : 0.f) * wpl;
    int xc0 = x0 & (WW - 1), xc1 = x1 & (WW - 1);
    int r0 = (y0 & (HH - 1)) << 6, r1 = (y1 & (HH - 1)) << 6;

    const __bf16* vbase = value + (size_t)b * (LQ * CC) + h * DH + g * 4;
    bf16x4 v00 = *(const bf16x4*)(vbase + (size_t)(r0 + xc0) * CC);
    bf16x4 v01 = *(const bf16x4*)(vbase + (size_t)(r0 + xc1) * CC);
    bf16x4 v10 = *(const bf16x4*)(vbase + (size_t)(r1 + xc0) * CC);
    bf16x4 v11 = *(const bf16x4*)(vbase + (size_t)(r1 + xc1) * CC);
    float w00 = mx0 * my0, w01 = mx1 * my0, w10 = mx0 * my1, w11 = mx1 * my1;

    f32x4 acc;
    #pragma unroll
    for (int e = 0; e < 4; ++e)
        acc[e] = w00 * (float)v00[e] + w01 * (float)v01[e]
               + w10 * (float)v10[e] + w11 * (float)v11[e];

    #pragma unroll
    for (int e = 0; e < 4; ++e) {
        acc[e] += __shfl_xor(acc[e], 16, 64);
        acc[e] += __shfl_xor(acc[e], 32, 64);
    }
    if (pp == 0) {
        bf16x4 o;
        o[0] = (__bf16)acc[0]; o[1] = (__bf16)acc[1];
        o[2] = (__bf16)acc[2]; o[3] = (__bf16)acc[3];
        *(bf16x4*)(out + (size_t)bq * CC + h * DH + g * 4) = o;
    }
}

// ---------------------------------------------------------------------------
// Launch
// ---------------------------------------------------------------------------
extern "C" void kernel_launch(void* const* d_in, const int* in_sizes, int n_in,
                              void* d_out, int out_size, void* d_ws, size_t ws_size,
                              hipStream_t stream) {
    const float* query = (const float*)d_in[0];
    const float* refp  = (const float*)d_in[1];
    const float* feat  = (const float*)d_in[2];
    const float* qn_g  = (const float*)d_in[7];
    const float* qn_b  = (const float*)d_in[8];
    const float* fn_g  = (const float*)d_in[9];
    const float* fn_b  = (const float*)d_in[10];
    const float* Wv    = (const float*)d_in[11];
    const float* bv    = (const float*)d_in[12];
    const float* Woff  = (const float*)d_in[13];
    const float* boff  = (const float*)d_in[14];
    const float* Watt  = (const float*)d_in[15];
    const float* batt  = (const float*)d_in[16];
    const float* Wout  = (const float*)d_in[17];
    const float* bout  = (const float*)d_in[18];
    const float* ffn_g = (const float*)d_in[19];
    const float* ffn_b = (const float*)d_in[20];
    const float* W1    = (const float*)d_in[21];
    const float* b1    = (const float*)d_in[22];
    const float* W2    = (const float*)d_in[23];
    const float* b2    = (const float*)d_in[24];
    float* out = (float*)d_out;

    // workspace layout (byte offsets)
    char* ws = (char*)d_ws;
    __bf16* WvT    = (__bf16*)(ws + 0);            // 1179648
    __bf16* WcombT = (__bf16*)(ws + 1179648);      // 192x768x2 = 294912 (slot 393216)
    __bf16* WoutT  = (__bf16*)(ws + 1572864);      // 1179648
    __bf16* W1T    = (__bf16*)(ws + 2752512);      // 192x768x2 = 294912 (slot 393216)
    __bf16* W2T    = (__bf16*)(ws + 3145728);      // 294912
    float*  offatt_f = (float*)(ws + 3670016);     // 9437184
    __bf16* h1_bf    = (__bf16*)offatt_f;          // reuse
    __bf16* bufA     = (__bf16*)(ws + 13107200);   // 25165824
    __bf16* qn_bf    = bufA;
    __bf16* value_bf = bufA;
    __bf16* bufB     = (__bf16*)(ws + 38273024);   // 25165824
    __bf16* fn_bf    = bufB;
    __bf16* samp_bf  = bufB;
    __bf16* h_bf     = bufB;
    __bf16* attn_bf  = (__bf16*)(ws + 63438848);   // 25165824

    dim3 blk(256);

    // 0. batched weight prep (one launch)
    PrepJobs jobs;
    jobs.j[0] = {Wv,   WvT,             768, 768, 768};
    jobs.j[1] = {Woff, WcombT,          768,  96,  96};
    jobs.j[2] = {Watt, WcombT + 96*768, 768,  48,  96};  // comb rows 96..191 (144..191 zero)
    jobs.j[3] = {Wout, WoutT,           768, 768, 768};
    jobs.j[4] = {W1,   W1T,             768, 192, 192};
    jobs.j[5] = {W2,   W2T,             192, 768, 768};
    prep_all<<<dim3(12, 12, 6), blk, 0, stream>>>(jobs);

    // 1. both input LayerNorms in one launch
    ln2_kernel<<<dim3(ROWS, 2), blk, 0, stream>>>(query, qn_g, qn_b, qn_bf,
                                                  feat,  fn_g, fn_b, fn_bf);

    // 2. offatt = qn @ [Woff|Watt] (N=144, Npad=192, f32 out) — 64x64 tiles
    gemm_bt64<<<dim3(3, ROWS / 64), blk, 0, stream>>>(
        qn_bf, WcombT, boff, 96, batt, offatt_f, ROWS, CC, 144, 0);
    // 3. value = fn @ Wv + bv (bf16 out)
    gemm_bt<<<dim3(6, ROWS / 128), blk, 0, stream>>>(
        fn_bf, WvT, bv, CC, nullptr, nullptr, value_bf, ROWS, CC, CC, 2);
    // 4. deformable sampling -> bf16
    sample_kernel<<<ROWS * NH_ / 4, blk, 0, stream>>>(value_bf, offatt_f, refp, samp_bf);
    // 5. attnres = query + samp @ Wout + bout (bf16 out)
    gemm_bt<<<dim3(6, ROWS / 128), blk, 0, stream>>>(
        samp_bf, WoutT, bout, CC, nullptr, query, attn_bf, ROWS, CC, CC, 2);
    // 6. h = LN(attnres) -> bf16
    ln_bf_kernel<<<ROWS, blk, 0, stream>>>(attn_bf, ffn_g, ffn_b, h_bf);
    // 7. h1 = gelu(h @ W1 + b1) -> bf16 (N=192) — 64x64 tiles
    gemm_bt64<<<dim3(3, ROWS / 64), blk, 0, stream>>>(
        h_bf, W1T, b1, HID, nullptr, h1_bf, ROWS, CC, HID, 1 | 2);
    // 8. out = attnres + h1 @ W2 + b2 (K=192, f32 out, bf16 res)
    gemm_bt<<<dim3(6, ROWS / 128), blk, 0, stream>>>(
        h1_bf, W2T, b2, CC, nullptr, attn_bf, out, ROWS, HID, CC, 4);
}